// Round 8
// baseline (209.977 us; speedup 1.0000x reference)
//
#include <hip/hip_runtime.h>

typedef unsigned short u16;
typedef __attribute__((ext_vector_type(8))) short short8;
typedef __attribute__((ext_vector_type(4))) float f32x4;

// ---------- helpers ----------
__device__ inline u16 f2bf(float f) {
    union { float f; unsigned u; } v; v.f = f;
    unsigned u = v.u;
    unsigned r = (u + 0x7FFFu + ((u >> 16) & 1u)) >> 16;
    return (u16)r;
}
__device__ inline float bf2f(u16 h) {
    union { unsigned u; float f; } v; v.u = ((unsigned)h) << 16;
    return v.f;
}
__device__ inline unsigned pack2(float lo, float hi) {
    return (unsigned)f2bf(lo) | ((unsigned)f2bf(hi) << 16);
}
// fast rcp/sqrt (~2^-21 rel err; tolerance is bf16-level 0.0078 -> free).
__device__ inline float frcp(float x) { return __builtin_amdgcn_rcpf(x); }
__device__ inline float fsqrt(float x) { return __builtin_amdgcn_sqrtf(x); }
__device__ inline float ftanh(float x) {
    float e = __expf(2.f * x);
    return 1.f - 2.f * frcp(e + 1.f);
}
__device__ inline float4 bf4f(ushort4 u) {
    float4 f; f.x = bf2f(u.x); f.y = bf2f(u.y); f.z = bf2f(u.z); f.w = bf2f(u.w);
    return f;
}

// 16B async global->LDS (phase-2 WT staging only; F staging must reg-stage for cast).
typedef const __attribute__((address_space(1))) void* gas_ptr;
typedef __attribute__((address_space(3))) void* las_ptr;
__device__ __forceinline__ void gl2lds16(const u16* g, u16* l) {
    __builtin_amdgcn_global_load_lds((gas_ptr)(const void*)g, (las_ptr)(void*)l, 16, 0, 0);
}

// ---------- kernel 1: W [256 s][512 d] fp32 -> WT [512 d][256 s] bf16 (tiny, 1 MB) ----------
__global__ __launch_bounds__(256) void wtrans_kernel(
    const float* __restrict__ W0, const float* __restrict__ W1,
    u16* __restrict__ WT0, u16* __restrict__ WT1)
{
    __shared__ u16 Wl[64][40];
    int idx2 = blockIdx.x;                  // 0..127
    int a = idx2 >> 6;
    int tile = idx2 & 63;
    int s0t = (tile >> 3) * 32, d0 = (tile & 7) * 64;
    const float* W = a ? W1 : W0;
    u16* WT = a ? WT1 : WT0;
    int t = threadIdx.x;
    #pragma unroll
    for (int i = 0; i < 2; ++i) {
        int idx = i * 1024 + t * 4;
        int sl = idx >> 6, dl = idx & 63;
        float4 v = *(const float4*)(W + (size_t)(s0t + sl) * 512 + d0 + dl);
        Wl[dl + 0][sl] = f2bf(v.x);
        Wl[dl + 1][sl] = f2bf(v.y);
        Wl[dl + 2][sl] = f2bf(v.z);
        Wl[dl + 3][sl] = f2bf(v.w);
    }
    __syncthreads();
    #pragma unroll
    for (int i = 0; i < 2; ++i) {
        int idx = i * 1024 + t * 4;
        int dl = idx >> 5, sl = idx & 31;
        ushort4 v;
        v.x = Wl[dl][sl + 0]; v.y = Wl[dl][sl + 1];
        v.z = Wl[dl][sl + 2]; v.w = Wl[dl][sl + 3];
        *(ushort4*)(WT + (size_t)(d0 + dl) * 256 + s0t + sl) = v;
    }
}

// ---------- kernel 2: FULLY FUSED: mask+cast+norms + cross-GEMM strip + Fa-GEMM + conv ----------
// Rounds 5-7 established: prep's structure is irrelevant to its cost, and
// ~115 us of wall-clock sits outside the big kernel. This version absorbs
// prep's work: each block reg-stages its fp32 G/S panels (mask+cast to bf16 in
// registers -> swizzled ds_write), accumulating row-norms from the masked fp32
// values (free FMAs + 8-lane shfl reduce). F0b/F1b are gone from HBM.
// Stage->MFMA edge uses raw s_barrier + explicit lgkmcnt(0) (NO vmcnt drain),
// so next-chunk preloads issued after the ds_writes stay in flight through the
// MFMA phase; the chunk-top __syncthreads drains them right where they're used.
// XCD-grouped job decode (round 7, verified: FETCH 175->48 MB).
__global__ __launch_bounds__(256) void fused_kernel(
    const float* __restrict__ F0r, const float* __restrict__ F1r,
    const float* __restrict__ m0, const float* __restrict__ m1,
    const u16* __restrict__ WT0, const u16* __restrict__ WT1,
    const float* __restrict__ cw, const float* __restrict__ cb,
    float* __restrict__ out)
{
    __shared__ __align__(16) u16 Al[36][264];     // A-strip (phase-2 A operand), 19.0 KB
    __shared__ __align__(16) u16 region[21136];   // 42.3 KB union (ph1: G[256][64]|S[48][64]; ph2: BlBuf|Fl)
    __shared__ float sqG_l[256];                  // row norms, computed in-block
    __shared__ float sqS_l[48];
    u16 (*Fl)[132] = (u16(*)[132])(region + 16384);

    int L = blockIdx.x + (blockIdx.y << 3) + (blockIdx.z << 9);
    int qq = L >> 6, rr = L & 63;
    int s0i = rr >> 3;
    int code = qq * 8 + (rr & 7);   // 0..127 = 2b+side; 8 s0-blocks of one code share an XCD
    int b = code >> 1, side = code & 1;
    int s0 = s0i * 32;

    const float* Gf = (side ? F1r : F0r) + (size_t)b * 131072;  // full-K operand (fp32)
    const float* Sf = (side ? F0r : F1r) + (size_t)b * 131072;  // strip operand (fp32)
    const float* mg = (side ? m1 : m0) + b * 256;               // mask for G rows AND conv F
    const float* ms = (side ? m0 : m1) + b * 256;               // mask for S rows
    const u16* WT = side ? WT1 : WT0;
    float* o = out + (size_t)side * 8388608 + (size_t)b * 131072;

    const int t = threadIdx.x;
    const int lane = t & 63, w = t >> 6;
    const int q = lane >> 4, lm = lane & 15;
    const int seg = t & 7, rbase = t >> 3;     // staging coords: 8 lanes per row

    // masks are chunk-invariant: preload once
    float mGr[8];
    #pragma unroll
    for (int i = 0; i < 8; ++i) mGr[i] = mg[rbase + i * 32];
    int rs1 = 32 + rbase;
    int cs0 = s0 - 2 + rbase; cs0 = cs0 < 0 ? 0 : (cs0 > 255 ? 255 : cs0);
    int cs1 = s0 - 2 + rs1;   cs1 = cs1 < 0 ? 0 : (cs1 > 255 ? 255 : cs1);
    float mS0 = ms[cs0];
    float mS1 = (t < 128) ? ms[cs1] : 0.f;

    sqG_l[t] = 0.f;
    if (t < 48) sqS_l[t] = 0.f;

    // ===== phase 1: A-strip GEMM with in-register mask/cast/norm staging =====
    f32x4 acc1[3][4];
    #pragma unroll
    for (int x = 0; x < 3; ++x)
        #pragma unroll
        for (int cn = 0; cn < 4; ++cn)
            acc1[x][cn] = (f32x4){0.f, 0.f, 0.f, 0.f};

    float4 gA[16], gS[4];
#define PH1_LOAD(kc) do {                                                      \
    _Pragma("unroll")                                                          \
    for (int i_ = 0; i_ < 8; ++i_) {                                           \
        const float* p_ = Gf + (size_t)(rbase + i_ * 32) * 512 + (kc) + seg * 8; \
        gA[2*i_]   = *(const float4*)p_;                                       \
        gA[2*i_+1] = *(const float4*)(p_ + 4);                                 \
    }                                                                          \
    { const float* p_ = Sf + (size_t)cs0 * 512 + (kc) + seg * 8;               \
      gS[0] = *(const float4*)p_; gS[1] = *(const float4*)(p_ + 4); }          \
    if (t < 128) {                                                             \
      const float* p_ = Sf + (size_t)cs1 * 512 + (kc) + seg * 8;               \
      gS[2] = *(const float4*)p_; gS[3] = *(const float4*)(p_ + 4); }          \
  } while (0)

// mask, accumulate row-norm partial, pack to bf16, swizzled ds_write
#define STAGE1(va, vb, mm, rr_, base_, sql_) do {                              \
    float4 a_ = va, d_ = vb; float m_ = mm;                                    \
    a_.x*=m_; a_.y*=m_; a_.z*=m_; a_.w*=m_;                                    \
    d_.x*=m_; d_.y*=m_; d_.z*=m_; d_.w*=m_;                                    \
    float ss_ = a_.x*a_.x + a_.y*a_.y + a_.z*a_.z + a_.w*a_.w                  \
              + d_.x*d_.x + d_.y*d_.y + d_.z*d_.z + d_.w*d_.w;                 \
    ss_ += __shfl_xor(ss_, 1); ss_ += __shfl_xor(ss_, 2); ss_ += __shfl_xor(ss_, 4); \
    uint4 u_;                                                                  \
    u_.x = pack2(a_.x, a_.y); u_.y = pack2(a_.z, a_.w);                        \
    u_.z = pack2(d_.x, d_.y); u_.w = pack2(d_.z, d_.w);                        \
    *(uint4*)&region[(base_) + (rr_) * 64 + (seg ^ ((rr_) & 7)) * 8] = u_;     \
    if (seg == 0) sql_[rr_] += ss_;                                            \
  } while (0)

    PH1_LOAD(0);

    for (int c = 0; c < 8; ++c) {
        __syncthreads();    // prev MFMA reads done; drains preloads right before use
        #pragma unroll
        for (int i = 0; i < 8; ++i) {
            int r = rbase + i * 32;
            STAGE1(gA[2*i], gA[2*i+1], mGr[i], r, 0, sqG_l);
        }
        STAGE1(gS[0], gS[1], mS0, rbase, 16384, sqS_l);
        if (t < 128)
            STAGE1(gS[2], gS[3], mS1, rs1, 16384, sqS_l);
        if (c < 7) PH1_LOAD((c + 1) * 64);  // in flight through MFMA (raw barrier below)
        asm volatile("s_waitcnt lgkmcnt(0)" ::: "memory");  // ds_writes visible
        __builtin_amdgcn_s_barrier();                       // NO vmcnt drain
        #pragma unroll
        for (int ks = 0; ks < 64; ks += 32) {
            int su = (((ks >> 3) + q) ^ (lm & 7)) * 8;      // read-side swizzle
            short8 af[3], bfr[4];
            #pragma unroll
            for (int x = 0; x < 3; ++x)
                af[x] = *(const short8*)&region[16384 + (x * 16 + lm) * 64 + su];
            #pragma unroll
            for (int cn = 0; cn < 4; ++cn)
                bfr[cn] = *(const short8*)&region[(w * 64 + cn * 16 + lm) * 64 + su];
            #pragma unroll
            for (int x = 0; x < 3; ++x)
                #pragma unroll
                for (int cn = 0; cn < 4; ++cn)
                    acc1[x][cn] = __builtin_amdgcn_mfma_f32_16x16x32_bf16(
                        af[x], bfr[cn], acc1[x][cn], 0, 0, 0);
        }
    }
    __syncthreads();        // MFMA reads + sq accumulation all visible
#undef PH1_LOAD
#undef STAGE1

    // epilogue: d2 -> A, write strip into Al (C-layout: row=x*16+q*4+r, col=w*64+cn*16+lm)
    #pragma unroll
    for (int x = 0; x < 3; ++x) {
        #pragma unroll
        for (int r = 0; r < 4; ++r) {
            int m = x * 16 + q * 4 + r;
            if (m < 36) {
                int s = s0 - 2 + m;
                bool ok = (unsigned)s < 256u;
                float sqs = sqS_l[m];           // garbage if !ok, unused
                #pragma unroll
                for (int cn = 0; cn < 4; ++cn) {
                    int j = w * 64 + cn * 16 + lm;
                    float d2 = fmaxf(sqs + sqG_l[j] - 2.f * acc1[x][cn][r], 0.f);
                    float a = ok ? frcp(1.f + fsqrt(d2)) : 0.f;
                    Al[m][j] = f2bf(a);
                }
            }
        }
    }
    // no barrier before STAGE_B: epilogue doesn't touch region[0..16384);
    // the n0-loop's kb_i=0 __syncthreads makes Al visible + drains the stage.

    // ===== phase 2: Fa-GEMM + conv (round-7 code; conv F now fp32+mask) =====
#define STAGE_B(bufo, nn, kb) do {                                             \
    _Pragma("unroll")                                                          \
    for (int i_ = 0; i_ < 4; ++i_) {                                           \
        int idx_ = i_ * 256 + t;                                               \
        int r_ = idx_ >> 3, seg_ = idx_ & 7;                                   \
        int ss_ = seg_ ^ (r_ & 7);                                             \
        gl2lds16(WT + (size_t)((nn) + r_) * 256 + (kb) + ss_ * 8,              \
                 &region[(bufo) + (i_ * 256 + w * 64) * 8]);                   \
    } } while (0)

    // A-fragment row pointers; x=2 rows >=36 dead (outputs discarded) -> clamp
    const u16* aRow[3];
    aRow[0] = &Al[lm][0];
    aRow[1] = &Al[16 + lm][0];
    aRow[2] = &Al[(lm < 4) ? (32 + lm) : 0][0];

    float w00 = cw[0], w01 = cw[1], w02 = cw[2];
    float w10 = cw[3], w11 = cw[4], w12 = cw[5];
    float bias = cb[0];
    const float third = 1.f / 3.f;
    const int g = t >> 5;               // 0..7: out-row group (4 rows)
    const int dl = (t & 31) * 4;        // d within chunk

    // conv row masks/addresses (n0-invariant)
    float mF[8]; int csF[8];
    #pragma unroll
    for (int k = 0; k < 8; ++k) {
        int s = s0 + g * 4 - 2 + k;
        bool ok = (unsigned)s < 256u;
        csF[k] = ok ? s : 0;
        mF[k] = ok ? mg[s] : 0.f;
    }

    STAGE_B(0, 0, 0);                   // prologue: n0=0, kb=0 -> buf0

    for (int n0 = 0; n0 < 512; n0 += 128) {
        f32x4 acc[3][2];
        #pragma unroll
        for (int x = 0; x < 3; ++x)
            #pragma unroll
            for (int y = 0; y < 2; ++y)
                acc[x][y] = (f32x4){0.f, 0.f, 0.f, 0.f};

        #pragma unroll
        for (int kb_i = 0; kb_i < 4; ++kb_i) {
            __syncthreads();            // drains stage kb_i (hidden under prior phase)
            if (kb_i < 3)
                STAGE_B(((kb_i + 1) & 1) * 8192, n0, (kb_i + 1) * 64);
            const int cbuf = (kb_i & 1) * 8192;
            const int kb = kb_i * 64;
            #pragma unroll
            for (int ks = 0; ks < 64; ks += 32) {
                short8 af[3], bfr[2];
                #pragma unroll
                for (int x = 0; x < 3; ++x)
                    af[x] = *(const short8*)(aRow[x] + kb + ks + q * 8);
                #pragma unroll
                for (int y = 0; y < 2; ++y) {
                    int rb = w * 32 + y * 16 + lm;
                    int su = (((ks >> 3) + q) ^ (lm & 7)) * 8;
                    bfr[y] = *(const short8*)&region[cbuf + rb * 64 + su];
                }
                #pragma unroll
                for (int x = 0; x < 3; ++x)
                    #pragma unroll
                    for (int y = 0; y < 2; ++y)
                        acc[x][y] = __builtin_amdgcn_mfma_f32_16x16x32_bf16(
                            af[x], bfr[y], acc[x][y], 0, 0, 0);
            }
        }

        // issue conv F-loads (fp32): latency overlaps Fl-write phase, drained at barrier
        float4 frg[8];
        #pragma unroll
        for (int k = 0; k < 8; ++k)
            frg[k] = *(const float4*)(Gf + (size_t)csF[k] * 512 + n0 + dl);

        // stage Fa (bf16) into Fl
        #pragma unroll
        for (int x = 0; x < 3; ++x)
            #pragma unroll
            for (int r = 0; r < 4; ++r) {
                int m = x * 16 + q * 4 + r;
                if (m < 36) {
                    #pragma unroll
                    for (int y = 0; y < 2; ++y)
                        Fl[m][w * 32 + y * 16 + lm] = f2bf(acc[x][y][r]);
                }
            }
        __syncthreads();                // Fl visible; frg complete

        // issue next n0's first WT chunk: hides under conv phase
        if (n0 < 384)
            STAGE_B(0, n0 + 128, 0);

        // conv + tanh + avgpool; thread: 4 out rows x 4 d
        float4 f[8], a[8];
        #pragma unroll
        for (int k = 0; k < 8; ++k) {
            f[k].x = frg[k].x * mF[k]; f[k].y = frg[k].y * mF[k];
            f[k].z = frg[k].z * mF[k]; f[k].w = frg[k].w * mF[k];
            a[k] = bf4f(*(const ushort4*)&Fl[g * 4 + k][dl]);
        }
        float4 ty[6];
        #pragma unroll
        for (int k = 0; k < 6; ++k) {
            float4 y;
            y.x = bias + w00*f[k].x + w01*f[k+1].x + w02*f[k+2].x + w10*a[k].x + w11*a[k+1].x + w12*a[k+2].x;
            y.y = bias + w00*f[k].y + w01*f[k+1].y + w02*f[k+2].y + w10*a[k].y + w11*a[k+1].y + w12*a[k+2].y;
            y.z = bias + w00*f[k].z + w01*f[k+1].z + w02*f[k+2].z + w10*a[k].z + w11*a[k+1].z + w12*a[k+2].z;
            y.w = bias + w00*f[k].w + w01*f[k+1].w + w02*f[k+2].w + w10*a[k].w + w11*a[k+1].w + w12*a[k+2].w;
            y.x = ftanh(y.x); y.y = ftanh(y.y); y.z = ftanh(y.z); y.w = ftanh(y.w);
            ty[k] = y;
        }
        #pragma unroll
        for (int r = 0; r < 4; ++r) {
            float4 res;
            res.x = (ty[r].x + ty[r+1].x + ty[r+2].x) * third;
            res.y = (ty[r].y + ty[r+1].y + ty[r+2].y) * third;
            res.z = (ty[r].z + ty[r+1].z + ty[r+2].z) * third;
            res.w = (ty[r].w + ty[r+1].w + ty[r+2].w) * third;
            *(float4*)(o + (size_t)(s0 + g * 4 + r) * 512 + n0 + dl) = res;
        }
        // next n0's kb_i=0 barrier separates conv reads of Fl from region rewrite
    }
#undef STAGE_B
}

// ---------- launcher ----------
extern "C" void kernel_launch(void* const* d_in, const int* in_sizes, int n_in,
                              void* d_out, int out_size, void* d_ws, size_t ws_size,
                              hipStream_t stream)
{
    const float* F0r = (const float*)d_in[0];
    const float* F1r = (const float*)d_in[1];
    const float* m0  = (const float*)d_in[2];
    const float* m1  = (const float*)d_in[3];
    const float* W0  = (const float*)d_in[4];
    const float* W1  = (const float*)d_in[5];
    const float* cw  = (const float*)d_in[6];
    const float* cb  = (const float*)d_in[7];
    float* out = (float*)d_out;

    char* ws = (char*)d_ws;
    u16* WT0 = (u16*)(ws);                // 256 KiB [D,S] bf16
    u16* WT1 = (u16*)(ws + 262144);       // 256 KiB

    wtrans_kernel<<<128, 256, 0, stream>>>(W0, W1, WT0, WT1);
    fused_kernel<<<dim3(8, 64, 2), 256, 0, stream>>>(F0r, F1r, m0, m1,
                                                     WT0, WT1, cw, cb, out);
}